// Round 7
// baseline (40.992 us; speedup 1.0000x reference)
//
#include <hip/hip_runtime.h>

typedef __attribute__((ext_vector_type(2))) float f32x2;
typedef __attribute__((ext_vector_type(4))) float f32x4;

#define NGRAPH 20000
#define GPT 7                 // graphs per stream (2 streams/thread -> 14 graphs/block)
#define STRIDE 36             // LDS row stride in floats (144 B; 16B-slot rotates r mod 8)
#define SB (STRIDE * 4)
#define BSTREAM (GPT * 36 * STRIDE)        // float offset of stream B region (9072)
#define BSTREAMB (BSTREAM * 4)             // byte offset (36288)
// Row byte map (virgin columns): L1 stage @0-15 (4 f32), L2 @16-63 (12 f32),
// L3 @64-127 (16 f32), L0 @128-135 (2 f32); pool reuses 0-127 post-B3/B4.

static __constant__ int c_indeg[36] = {
    7,5,5,7,6,5,5,6,9,9,9,9,5,7,7,5,5,6,6,5,7,7,5,5,7,5,5,7,5,6,6,5,6,5,5,6
};
static __constant__ signed char c_adj[36][9] = {
    {3,7,9,6,1,18,10,0,0},      {0,6,7,2,19,0,0,0,0},
    {1,3,33,32,20,0,0,0,0},     {2,10,0,32,21,33,9,0,0},
    {7,9,5,27,22,26,0,0,0},     {4,6,26,23,27,0,0,0,0},
    {5,7,1,24,0,0,0,0,0},       {6,9,4,0,25,1,0,0,0},
    {11,24,27,9,13,18,17,26,14},{8,27,24,3,10,4,7,0,27},
    {9,0,11,21,35,32,3,28,20},  {10,13,8,20,30,29,14,29,21},
    {15,19,18,13,30,0,0,0,0},   {12,18,8,19,14,31,11,0,0},
    {13,11,8,15,29,32,28,0,0},  {14,12,28,33,29,0,0,0,0},
    {19,25,17,34,24,0,0,0,0},   {16,24,8,18,35,25,0,0,0},
    {17,8,0,19,13,12,0,0,0},    {18,1,16,12,13,0,0,0,0},
    {23,30,11,2,31,10,21,0,0},  {20,35,10,3,34,11,22,0,0},
    {21,34,4,35,23,0,0,0,0},    {22,31,5,30,20,0,0,0,0},
    {27,6,16,25,17,8,9,0,0},    {24,7,17,26,16,0,0,0,0},
    {25,5,8,27,4,0,0,0,0},      {26,4,9,5,24,9,8,0,0},
    {31,15,10,14,29,0,0,0,0},   {28,14,11,11,15,30,0,0,0},
    {29,11,12,31,20,23,0,0,0},  {30,13,28,23,20,0,0,0,0},
    {35,3,10,14,2,33,0,0,0},    {32,2,15,3,34,0,0,0,0},
    {33,16,35,22,21,0,0,0,0},   {34,10,17,32,21,22,0,0,0},
};
static __constant__ float c_inv[36] = {
    0.35355339f,0.40824829f,0.40824829f,0.35355339f,0.37796447f,0.40824829f,
    0.40824829f,0.37796447f,0.31622777f,0.31622777f,0.31622777f,0.31622777f,
    0.40824829f,0.35355339f,0.35355339f,0.40824829f,0.40824829f,0.37796447f,
    0.37796447f,0.40824829f,0.35355339f,0.35355339f,0.40824829f,0.40824829f,
    0.35355339f,0.40824829f,0.40824829f,0.35355339f,0.40824829f,0.37796447f,
    0.37796447f,0.40824829f,0.37796447f,0.40824829f,0.40824829f,0.37796447f,
};

static __device__ __forceinline__ f32x2 relu2(f32x2 v) {
    return __builtin_elementwise_max(v, (f32x2){0.f, 0.f});
}

// Transforms (weights uniform -> SGPR broadcast; CSE'd across the two calls).
static __device__ __forceinline__ void xf1(const float* a, const float* W1,
                                           const float* b1, f32x2* h) {
    f32x2 z[6];
    const f32x2* bv = (const f32x2*)b1;
#pragma unroll
    for (int j = 0; j < 6; ++j) z[j] = bv[j];
    const f32x2* Wv = (const f32x2*)W1;
#pragma unroll
    for (int i = 0; i < 4; ++i) {
        const f32x2 av = {a[i], a[i]};
#pragma unroll
        for (int j = 0; j < 6; ++j)
            z[j] = __builtin_elementwise_fma(av, Wv[i * 6 + j], z[j]);
    }
#pragma unroll
    for (int j = 0; j < 6; ++j) h[j] = relu2(z[j]);
}
static __device__ __forceinline__ void xf2(const float* a, const float* W2,
                                           const float* b2, f32x2* h) {
    f32x2 z[8];
    const f32x2* bv = (const f32x2*)b2;
#pragma unroll
    for (int j = 0; j < 8; ++j) z[j] = bv[j];
    const f32x2* Wv = (const f32x2*)W2;
#pragma unroll
    for (int i = 0; i < 12; ++i) {
        const f32x2 av = {a[i], a[i]};
#pragma unroll
        for (int j = 0; j < 8; ++j)
            z[j] = __builtin_elementwise_fma(av, Wv[i * 8 + j], z[j]);
    }
#pragma unroll
    for (int j = 0; j < 8; ++j) h[j] = relu2(z[j]);
}
static __device__ __forceinline__ void xf3(const float* a, const float* W3,
                                           const float* b3, f32x2* h) {
    f32x2 z[16];
    const f32x2* bv = (const f32x2*)b3;
#pragma unroll
    for (int j = 0; j < 16; ++j) z[j] = bv[j];
    const f32x2* Wv = (const f32x2*)W3;
#pragma unroll
    for (int i = 0; i < 16; ++i) {
        const f32x2 av = {a[i], a[i]};
#pragma unroll
        for (int j = 0; j < 16; ++j)
            z[j] = __builtin_elementwise_fma(av, Wv[i * 16 + j], z[j]);
    }
#pragma unroll
    for (int j = 0; j < 16; ++j) h[j] = relu2(z[j]);
}

extern "C" __global__ __launch_bounds__(256, 2)
void gcn_fused(const float* __restrict__ x,
               const float* __restrict__ W0, const float* __restrict__ b0,
               const float* __restrict__ W1, const float* __restrict__ b1,
               const float* __restrict__ W2, const float* __restrict__ b2,
               const float* __restrict__ W3, const float* __restrict__ b3,
               const float* __restrict__ Wfc, const float* __restrict__ bfc,
               float* __restrict__ out)
{
    __shared__ float L[2 * BSTREAM];    // 14 graphs x 36 rows x 144 B = 72,576 B

    const int t = threadIdx.x;
    const int g = t / 36;
    const int v = t - g * 36;
    const bool act = (g < GPT);
    const int gq = act ? g : GPT - 1;
    const int vc = act ? v : 0;
    const int GA = blockIdx.x * (2 * GPT) + g;        // stream A graph
    const int GB = GA + GPT;                          // stream B graph
    const int GcA = (act && GA < NGRAPH) ? GA : 0;
    const int GcB = (act && GB < NGRAPH) ? GB : 0;
    const bool okB = (GB < NGRAPH);

    const int nd = c_indeg[vc];
    const float inv_v = c_inv[vc];
    int aoff[9], boff[9];
#pragma unroll
    for (int k = 0; k < 9; ++k) {
        aoff[k] = (gq * 36 + (int)c_adj[vc][k]) * SB;
        boff[k] = aoff[k] + BSTREAMB;
    }
    float* srowA = &L[(gq * 36 + vc) * STRIDE];
    float* srowB = srowA + BSTREAM;
    const char* Lb = (const char*)L;

    // ------------------- Layer 0: fi=2 -> fo=4 (stage @128) -----------------
    f32x2 h0A[2], h0B[2];
    {
        const float2* x2 = (const float2*)x;
        const float2 xA = x2[(size_t)GcA * 36 + vc];
        const float2 xB = x2[(size_t)GcB * 36 + vc];
        const f32x2 sA = {xA.x * inv_v, xA.y * inv_v};
        const f32x2 sB = {xB.x * inv_v, xB.y * inv_v};
        if (act) { *(f32x2*)&srowA[32] = sA; *(f32x2*)&srowB[32] = sB; }
        __syncthreads();                                          // B0
        f32x2 cA = sA, cB = sB;
#pragma unroll
        for (int k = 0; k < 5; ++k) {
            cA += *(const f32x2*)(Lb + aoff[k] + 128);
            cB += *(const f32x2*)(Lb + boff[k] + 128);
        }
        if (nd > 5) { cA += *(const f32x2*)(Lb + aoff[5] + 128);
                      cB += *(const f32x2*)(Lb + boff[5] + 128); }
        if (nd > 6) { cA += *(const f32x2*)(Lb + aoff[6] + 128);
                      cB += *(const f32x2*)(Lb + boff[6] + 128); }
        if (nd > 7) { cA += *(const f32x2*)(Lb + aoff[7] + 128);
                      cB += *(const f32x2*)(Lb + boff[7] + 128);
                      cA += *(const f32x2*)(Lb + aoff[8] + 128);
                      cB += *(const f32x2*)(Lb + boff[8] + 128); }
        const f32x2* W0v = (const f32x2*)W0;
        const f32x2* b0v = (const f32x2*)b0;
        {
            const float a0 = cA.x * inv_v, a1 = cA.y * inv_v;
            const f32x2 a0v = {a0, a0}, a1v = {a1, a1};
            h0A[0] = relu2(__builtin_elementwise_fma(a0v, W0v[0],
                     __builtin_elementwise_fma(a1v, W0v[2], b0v[0])));
            h0A[1] = relu2(__builtin_elementwise_fma(a0v, W0v[1],
                     __builtin_elementwise_fma(a1v, W0v[3], b0v[1])));
        }
        {
            const float a0 = cB.x * inv_v, a1 = cB.y * inv_v;
            const f32x2 a0v = {a0, a0}, a1v = {a1, a1};
            h0B[0] = relu2(__builtin_elementwise_fma(a0v, W0v[0],
                     __builtin_elementwise_fma(a1v, W0v[2], b0v[0])));
            h0B[1] = relu2(__builtin_elementwise_fma(a0v, W0v[1],
                     __builtin_elementwise_fma(a1v, W0v[3], b0v[1])));
        }
    }

    // ------------------- Layer 1: fi=4 -> fo=12 (stage @0) ------------------
    f32x2 h1A[6], h1B[6];
    {
        const f32x2 iv = {inv_v, inv_v};
        const f32x2 sA0 = h0A[0] * iv, sA1 = h0A[1] * iv;
        const f32x2 sB0 = h0B[0] * iv, sB1 = h0B[1] * iv;
        if (act) {
            *(f32x4*)&srowA[0] = (f32x4){sA0.x, sA0.y, sA1.x, sA1.y};
            *(f32x4*)&srowB[0] = (f32x4){sB0.x, sB0.y, sB1.x, sB1.y};
        }
        __syncthreads();                                          // B1
        f32x4 cA = {sA0.x, sA0.y, sA1.x, sA1.y};
        f32x4 cB = {sB0.x, sB0.y, sB1.x, sB1.y};
#pragma unroll
        for (int k = 0; k < 5; ++k) {
            cA += *(const f32x4*)(Lb + aoff[k]);
            cB += *(const f32x4*)(Lb + boff[k]);
        }
        if (nd > 5) { cA += *(const f32x4*)(Lb + aoff[5]);
                      cB += *(const f32x4*)(Lb + boff[5]); }
        if (nd > 6) { cA += *(const f32x4*)(Lb + aoff[6]);
                      cB += *(const f32x4*)(Lb + boff[6]); }
        if (nd > 7) { cA += *(const f32x4*)(Lb + aoff[7]);
                      cB += *(const f32x4*)(Lb + boff[7]);
                      cA += *(const f32x4*)(Lb + aoff[8]);
                      cB += *(const f32x4*)(Lb + boff[8]); }
        float aA[4], aB[4];
#pragma unroll
        for (int i = 0; i < 4; ++i) { aA[i] = cA[i] * inv_v; aB[i] = cB[i] * inv_v; }
        xf1(aA, W1, b1, h1A);
        xf1(aB, W1, b1, h1B);
    }

    // ------------------- Layer 2: fi=12 -> fo=16 (stage @16) ----------------
    f32x2 h2A[8], h2B[8];
    {
        const f32x2 iv = {inv_v, inv_v};
        f32x2 sA[6], sB[6];
#pragma unroll
        for (int j = 0; j < 6; ++j) { sA[j] = h1A[j] * iv; sB[j] = h1B[j] * iv; }
        if (act) {
            *(f32x4*)&srowA[4]  = (f32x4){sA[0].x, sA[0].y, sA[1].x, sA[1].y};
            *(f32x4*)&srowA[8]  = (f32x4){sA[2].x, sA[2].y, sA[3].x, sA[3].y};
            *(f32x4*)&srowA[12] = (f32x4){sA[4].x, sA[4].y, sA[5].x, sA[5].y};
            *(f32x4*)&srowB[4]  = (f32x4){sB[0].x, sB[0].y, sB[1].x, sB[1].y};
            *(f32x4*)&srowB[8]  = (f32x4){sB[2].x, sB[2].y, sB[3].x, sB[3].y};
            *(f32x4*)&srowB[12] = (f32x4){sB[4].x, sB[4].y, sB[5].x, sB[5].y};
        }
        __syncthreads();                                          // B2
        f32x4 cA0 = {sA[0].x, sA[0].y, sA[1].x, sA[1].y};
        f32x4 cA1 = {sA[2].x, sA[2].y, sA[3].x, sA[3].y};
        f32x4 cA2 = {sA[4].x, sA[4].y, sA[5].x, sA[5].y};
        f32x4 cB0 = {sB[0].x, sB[0].y, sB[1].x, sB[1].y};
        f32x4 cB1 = {sB[2].x, sB[2].y, sB[3].x, sB[3].y};
        f32x4 cB2 = {sB[4].x, sB[4].y, sB[5].x, sB[5].y};
#pragma unroll
        for (int k = 0; k < 5; ++k) {
            const char* pa = Lb + aoff[k] + 16;
            const char* pb = Lb + boff[k] + 16;
            cA0 += *(const f32x4*)(pa);      cB0 += *(const f32x4*)(pb);
            cA1 += *(const f32x4*)(pa + 16); cB1 += *(const f32x4*)(pb + 16);
            cA2 += *(const f32x4*)(pa + 32); cB2 += *(const f32x4*)(pb + 32);
        }
        if (nd > 5) { const char* pa = Lb + aoff[5] + 16; const char* pb = Lb + boff[5] + 16;
            cA0 += *(const f32x4*)(pa);      cB0 += *(const f32x4*)(pb);
            cA1 += *(const f32x4*)(pa + 16); cB1 += *(const f32x4*)(pb + 16);
            cA2 += *(const f32x4*)(pa + 32); cB2 += *(const f32x4*)(pb + 32); }
        if (nd > 6) { const char* pa = Lb + aoff[6] + 16; const char* pb = Lb + boff[6] + 16;
            cA0 += *(const f32x4*)(pa);      cB0 += *(const f32x4*)(pb);
            cA1 += *(const f32x4*)(pa + 16); cB1 += *(const f32x4*)(pb + 16);
            cA2 += *(const f32x4*)(pa + 32); cB2 += *(const f32x4*)(pb + 32); }
        if (nd > 7) {
            const char* pa = Lb + aoff[7] + 16; const char* pb = Lb + boff[7] + 16;
            cA0 += *(const f32x4*)(pa);      cB0 += *(const f32x4*)(pb);
            cA1 += *(const f32x4*)(pa + 16); cB1 += *(const f32x4*)(pb + 16);
            cA2 += *(const f32x4*)(pa + 32); cB2 += *(const f32x4*)(pb + 32);
            const char* qa = Lb + aoff[8] + 16; const char* qb = Lb + boff[8] + 16;
            cA0 += *(const f32x4*)(qa);      cB0 += *(const f32x4*)(qb);
            cA1 += *(const f32x4*)(qa + 16); cB1 += *(const f32x4*)(qb + 16);
            cA2 += *(const f32x4*)(qa + 32); cB2 += *(const f32x4*)(qb + 32);
        }
        float aA[12], aB[12];
#pragma unroll
        for (int i = 0; i < 4; ++i) {
            aA[i] = cA0[i] * inv_v; aA[4+i] = cA1[i] * inv_v; aA[8+i] = cA2[i] * inv_v;
            aB[i] = cB0[i] * inv_v; aB[4+i] = cB1[i] * inv_v; aB[8+i] = cB2[i] * inv_v;
        }
        xf2(aA, W2, b2, h2A);
        xf2(aB, W2, b2, h2B);
    }

    // ------------------- Layer 3: fi=16 -> fo=32 (stage @64) ----------------
    f32x2 h3A[16], h3B[16];
    {
        const f32x2 iv = {inv_v, inv_v};
        f32x2 sA[8], sB[8];
#pragma unroll
        for (int j = 0; j < 8; ++j) { sA[j] = h2A[j] * iv; sB[j] = h2B[j] * iv; }
        if (act) {
#pragma unroll
            for (int q = 0; q < 4; ++q) {
                *(f32x4*)&srowA[16 + q*4] =
                    (f32x4){sA[2*q].x, sA[2*q].y, sA[2*q+1].x, sA[2*q+1].y};
                *(f32x4*)&srowB[16 + q*4] =
                    (f32x4){sB[2*q].x, sB[2*q].y, sB[2*q+1].x, sB[2*q+1].y};
            }
        }
        __syncthreads();                                          // B3
        f32x4 cA0 = {sA[0].x, sA[0].y, sA[1].x, sA[1].y};
        f32x4 cA1 = {sA[2].x, sA[2].y, sA[3].x, sA[3].y};
        f32x4 cA2 = {sA[4].x, sA[4].y, sA[5].x, sA[5].y};
        f32x4 cA3 = {sA[6].x, sA[6].y, sA[7].x, sA[7].y};
        f32x4 cB0 = {sB[0].x, sB[0].y, sB[1].x, sB[1].y};
        f32x4 cB1 = {sB[2].x, sB[2].y, sB[3].x, sB[3].y};
        f32x4 cB2 = {sB[4].x, sB[4].y, sB[5].x, sB[5].y};
        f32x4 cB3 = {sB[6].x, sB[6].y, sB[7].x, sB[7].y};
#pragma unroll
        for (int k = 0; k < 5; ++k) {
            const char* pa = Lb + aoff[k] + 64;
            const char* pb = Lb + boff[k] + 64;
            cA0 += *(const f32x4*)(pa);      cB0 += *(const f32x4*)(pb);
            cA1 += *(const f32x4*)(pa + 16); cB1 += *(const f32x4*)(pb + 16);
            cA2 += *(const f32x4*)(pa + 32); cB2 += *(const f32x4*)(pb + 32);
            cA3 += *(const f32x4*)(pa + 48); cB3 += *(const f32x4*)(pb + 48);
        }
        if (nd > 5) { const char* pa = Lb + aoff[5] + 64; const char* pb = Lb + boff[5] + 64;
            cA0 += *(const f32x4*)(pa);      cB0 += *(const f32x4*)(pb);
            cA1 += *(const f32x4*)(pa + 16); cB1 += *(const f32x4*)(pb + 16);
            cA2 += *(const f32x4*)(pa + 32); cB2 += *(const f32x4*)(pb + 32);
            cA3 += *(const f32x4*)(pa + 48); cB3 += *(const f32x4*)(pb + 48); }
        if (nd > 6) { const char* pa = Lb + aoff[6] + 64; const char* pb = Lb + boff[6] + 64;
            cA0 += *(const f32x4*)(pa);      cB0 += *(const f32x4*)(pb);
            cA1 += *(const f32x4*)(pa + 16); cB1 += *(const f32x4*)(pb + 16);
            cA2 += *(const f32x4*)(pa + 32); cB2 += *(const f32x4*)(pb + 32);
            cA3 += *(const f32x4*)(pa + 48); cB3 += *(const f32x4*)(pb + 48); }
        if (nd > 7) {
            const char* pa = Lb + aoff[7] + 64; const char* pb = Lb + boff[7] + 64;
            cA0 += *(const f32x4*)(pa);      cB0 += *(const f32x4*)(pb);
            cA1 += *(const f32x4*)(pa + 16); cB1 += *(const f32x4*)(pb + 16);
            cA2 += *(const f32x4*)(pa + 32); cB2 += *(const f32x4*)(pb + 32);
            cA3 += *(const f32x4*)(pa + 48); cB3 += *(const f32x4*)(pb + 48);
            const char* qa = Lb + aoff[8] + 64; const char* qb = Lb + boff[8] + 64;
            cA0 += *(const f32x4*)(qa);      cB0 += *(const f32x4*)(qb);
            cA1 += *(const f32x4*)(qa + 16); cB1 += *(const f32x4*)(qb + 16);
            cA2 += *(const f32x4*)(qa + 32); cB2 += *(const f32x4*)(qb + 32);
            cA3 += *(const f32x4*)(qa + 48); cB3 += *(const f32x4*)(qb + 48);
        }
        float aA[16], aB[16];
#pragma unroll
        for (int i = 0; i < 4; ++i) {
            aA[i] = cA0[i] * inv_v; aA[4+i]  = cA1[i] * inv_v;
            aA[8+i] = cA2[i] * inv_v; aA[12+i] = cA3[i] * inv_v;
            aB[i] = cB0[i] * inv_v; aB[4+i]  = cB1[i] * inv_v;
            aB[8+i] = cB2[i] * inv_v; aB[12+i] = cB3[i] * inv_v;
        }
        xf3(aA, W3, b3, h3A);
        xf3(aB, W3, b3, h3B);
    }

    // ---- Pool-lo stage (cols 0-11; disjoint from L3-agg bytes 64-127) ------
    if (act) {
        *(f32x4*)&srowA[0] = (f32x4){h3A[0].x, h3A[0].y, h3A[1].x, h3A[1].y};
        *(f32x4*)&srowA[4] = (f32x4){h3A[2].x, h3A[2].y, h3A[3].x, h3A[3].y};
        *(f32x4*)&srowA[8] = (f32x4){h3A[4].x, h3A[4].y, h3A[5].x, h3A[5].y};
        *(f32x4*)&srowB[0] = (f32x4){h3B[0].x, h3B[0].y, h3B[1].x, h3B[1].y};
        *(f32x4*)&srowB[4] = (f32x4){h3B[2].x, h3B[2].y, h3B[3].x, h3B[3].y};
        *(f32x4*)&srowB[8] = (f32x4){h3B[4].x, h3B[4].y, h3B[5].x, h3B[5].y};
    }
    __syncthreads();   // B4: L3-agg reads drained + pool-lo visible
    if (act) {
#pragma unroll
        for (int q = 0; q < 5; ++q) {
            *(f32x4*)&srowA[12 + q*4] =
                (f32x4){h3A[6+2*q].x, h3A[6+2*q].y, h3A[7+2*q].x, h3A[7+2*q].y};
            *(f32x4*)&srowB[12 + q*4] =
                (f32x4){h3B[6+2*q].x, h3B[6+2*q].y, h3B[7+2*q].x, h3B[7+2*q].y};
        }
    }
    __syncthreads();                                              // B5

    // ---- Pool (32 lanes/graph column scan, both streams) + shuffle-FC ------
    if (t < GPT * 32) {
        const int pg = t >> 5, pf = t & 31;
        const int PA = blockIdx.x * (2 * GPT) + pg;   // always < NGRAPH
        const int PB = PA + GPT;
        const float* colA = &L[(pg * 36) * STRIDE + pf];
        const float* colB = colA + BSTREAM;
        float mxA = -1e30f, smA = 0.f, mxB = -1e30f, smB = 0.f;
#pragma unroll
        for (int u = 0; u < 36; ++u) {
            const float vA = colA[u * STRIDE];
            const float vB = colB[u * STRIDE];
            mxA = fmaxf(mxA, vA); smA += vA;
            mxB = fmaxf(mxB, vB); smB += vB;
        }
        const float gapA = smA * (1.0f / 36.0f);
        const float gapB = smB * (1.0f / 36.0f);
        {
            float* ho = out + (size_t)NGRAPH * 7 + (size_t)PA * 64;
            ho[pf] = mxA; ho[32 + pf] = gapA;
        }
        if (PB < NGRAPH) {
            float* ho = out + (size_t)NGRAPH * 7 + (size_t)PB * 64;
            ho[pf] = mxB; ho[32 + pf] = gapB;
        }
        float pA[7], pB[7];
        const float* wr0 = Wfc + pf * 7;
        const float* wr1 = Wfc + (32 + pf) * 7;
#pragma unroll
        for (int o = 0; o < 7; ++o) {
            pA[o] = fmaf(mxA, wr0[o], gapA * wr1[o]);
            pB[o] = fmaf(mxB, wr0[o], gapB * wr1[o]);
        }
#pragma unroll
        for (int m = 16; m >= 1; m >>= 1) {
#pragma unroll
            for (int o = 0; o < 7; ++o) {
                pA[o] += __shfl_xor(pA[o], m, 32);
                pB[o] += __shfl_xor(pB[o], m, 32);
            }
        }
        if (pf < 7) {
            float wA = pA[0], wB = pB[0];
            wA = (pf == 1) ? pA[1] : wA;  wB = (pf == 1) ? pB[1] : wB;
            wA = (pf == 2) ? pA[2] : wA;  wB = (pf == 2) ? pB[2] : wB;
            wA = (pf == 3) ? pA[3] : wA;  wB = (pf == 3) ? pB[3] : wB;
            wA = (pf == 4) ? pA[4] : wA;  wB = (pf == 4) ? pB[4] : wB;
            wA = (pf == 5) ? pA[5] : wA;  wB = (pf == 5) ? pB[5] : wB;
            wA = (pf == 6) ? pA[6] : wA;  wB = (pf == 6) ? pB[6] : wB;
            out[(size_t)PA * 7 + pf] = fmaxf(wA + bfc[pf], 0.f);
            if (PB < NGRAPH)
                out[(size_t)PB * 7 + pf] = fmaxf(wB + bfc[pf], 0.f);
        }
    }
}

extern "C" void kernel_launch(void* const* d_in, const int* in_sizes, int n_in,
                              void* d_out, int out_size, void* d_ws, size_t ws_size,
                              hipStream_t stream) {
    (void)in_sizes; (void)n_in; (void)d_ws; (void)ws_size; (void)out_size;
    const float* x   = (const float*)d_in[0];
    const float* W0  = (const float*)d_in[4];
    const float* b0  = (const float*)d_in[5];
    const float* W1  = (const float*)d_in[6];
    const float* b1  = (const float*)d_in[7];
    const float* W2  = (const float*)d_in[8];
    const float* b2  = (const float*)d_in[9];
    const float* W3  = (const float*)d_in[10];
    const float* b3  = (const float*)d_in[11];
    const float* Wfc = (const float*)d_in[12];
    const float* bfc = (const float*)d_in[13];
    float* out = (float*)d_out;

    const int nblocks = (NGRAPH + 2 * GPT - 1) / (2 * GPT);  // 1429
    hipLaunchKernelGGL(gcn_fused, dim3(nblocks), dim3(256), 0, stream,
                       x, W0, b0, W1, b1, W2, b2, W3, b3, Wfc, bfc, out);
}